// Round 1
// baseline (225.798 us; speedup 1.0000x reference)
//
#include <hip/hip_runtime.h>

// ChannelKiller: out[b,c,t] = x[b,c,t] * (c==0 ? 1.0f : 0.5f)
// Shapes: B=16, C=8, T=262144 (fp32) -> n = 33,554,432 floats, n4 = 8,388,608 float4s.
// T/4 = 65536 float4s per (b,c) channel-run; channel of float4 index i4 = (i4>>16)&7.
//
// Memory-bound: 268 MB total traffic, floor ~42.6 us @ 6.3 TB/s achievable.
//
// Structure: each block owns 1024 consecutive float4s (256 threads x 4).
// Since 1024 divides 65536, the channel (and thus the scale) is uniform per
// block: c = (blockIdx.x >> 6) & 7 -> scale lives in an SGPR, zero per-lane
// index math. The 4 loads per thread are independent (issued back-to-back,
// MLP=4) before any store, instead of the previous dependent grid-stride loop.

__global__ void __launch_bounds__(256)
channel_killer_kernel(const float4* __restrict__ x, float4* __restrict__ out) {
    const int base = blockIdx.x * 1024 + threadIdx.x;
    // Block-uniform scale: 64 blocks per channel-run of 65536 float4s.
    const float s = ((blockIdx.x >> 6) & 7) == 0 ? 1.0f : 0.5f;

    // 4 independent coalesced loads (global_load_dwordx4 x4 in flight).
    float4 v0 = x[base];
    float4 v1 = x[base + 256];
    float4 v2 = x[base + 512];
    float4 v3 = x[base + 768];

    v0.x *= s; v0.y *= s; v0.z *= s; v0.w *= s;
    v1.x *= s; v1.y *= s; v1.z *= s; v1.w *= s;
    v2.x *= s; v2.y *= s; v2.z *= s; v2.w *= s;
    v3.x *= s; v3.y *= s; v3.z *= s; v3.w *= s;

    out[base]       = v0;
    out[base + 256] = v1;
    out[base + 512] = v2;
    out[base + 768] = v3;
}

extern "C" void kernel_launch(void* const* d_in, const int* in_sizes, int n_in,
                              void* d_out, int out_size, void* d_ws, size_t ws_size,
                              hipStream_t stream) {
    const float4* x = (const float4*)d_in[0];
    float4* out = (float4*)d_out;
    const int n = in_sizes[0];          // 33,554,432 floats
    const int n4 = n >> 2;              // 8,388,608 float4s

    const int block = 256;
    const int grid = n4 >> 10;          // 1024 float4s per block -> 8192 blocks (exact)
    channel_killer_kernel<<<grid, block, 0, stream>>>(x, out);
}

// Round 2
// 218.132 us; speedup vs baseline: 1.0351x; 1.0351x over previous
//
#include <hip/hip_runtime.h>

// ChannelKiller: out[b,c,t] = x[b,c,t] * (c==0 ? 1.0f : 0.5f)
// Shapes: B=16, C=8, T=262144 (fp32) -> n = 33,554,432 floats, n4 = 8,388,608 float4s.
// T/4 = 65536 float4s per (b,c) channel-run; channel of float4 index i4 = (i4>>16)&7.
//
// Memory-bound: 268 MB total traffic, floor ~42.6 us @ 6.3 TB/s achievable.
//
// Round 2: pure streaming, zero reuse -> mark ALL loads and stores nontemporal
// (nt cache hint: no L2/L3 allocation). Theory: the kernel's 268 MB stream
// thrashes L3 (reads+writes both allocate, evicting each other), capping it at
// ~4.1 TB/s while the write-only fills hit 6.7 TB/s. NT hints stream past the
// caches. Structure otherwise identical to round 1 (block-uniform scale,
// 4 independent float4 loads/stores per thread, MLP=4).

using f32x4 = __attribute__((ext_vector_type(4))) float;

__global__ void __launch_bounds__(256)
channel_killer_kernel(const f32x4* __restrict__ x, f32x4* __restrict__ out) {
    const int base = blockIdx.x * 1024 + threadIdx.x;
    // Block-uniform scale: 64 blocks per channel-run of 65536 float4s.
    const float s = ((blockIdx.x >> 6) & 7) == 0 ? 1.0f : 0.5f;

    f32x4 v0 = __builtin_nontemporal_load(&x[base]);
    f32x4 v1 = __builtin_nontemporal_load(&x[base + 256]);
    f32x4 v2 = __builtin_nontemporal_load(&x[base + 512]);
    f32x4 v3 = __builtin_nontemporal_load(&x[base + 768]);

    v0 *= s;
    v1 *= s;
    v2 *= s;
    v3 *= s;

    __builtin_nontemporal_store(v0, &out[base]);
    __builtin_nontemporal_store(v1, &out[base + 256]);
    __builtin_nontemporal_store(v2, &out[base + 512]);
    __builtin_nontemporal_store(v3, &out[base + 768]);
}

extern "C" void kernel_launch(void* const* d_in, const int* in_sizes, int n_in,
                              void* d_out, int out_size, void* d_ws, size_t ws_size,
                              hipStream_t stream) {
    const f32x4* x = (const f32x4*)d_in[0];
    f32x4* out = (f32x4*)d_out;
    const int n = in_sizes[0];          // 33,554,432 floats
    const int n4 = n >> 2;              // 8,388,608 float4s

    const int block = 256;
    const int grid = n4 >> 10;          // 1024 float4s per block -> 8192 blocks (exact)
    channel_killer_kernel<<<grid, block, 0, stream>>>(x, out);
}